// Round 7
// baseline (1260.100 us; speedup 1.0000x reference)
//
#include <hip/hip_runtime.h>
#include <hip/hip_fp16.h>

typedef _Float16 f16;
typedef _Float16 f16x8 __attribute__((ext_vector_type(8)));
typedef _Float16 f16x4 __attribute__((ext_vector_type(4)));
typedef float f32x4 __attribute__((ext_vector_type(4)));

#define L2E 1.4426950408889634f

// workspace layout (bytes)
#define WQ_OFF   0         // 768*256 f16   qkv weight, row-major [n][k]
#define PW_OFF   393216    // 256*256 f16   proj weight, row-major [n][k]
#define QB_OFF   524288    // 768 f32       concat qkv bias (k-bias = 0)
#define SC_OFF   527360    // 8 f32         exp(min(logit_scale, ln100))
#define TBL_OFF  527616    // 225*8 f32     cpb mlp table
#define BB_OFF   535040    // 32768 f32     folded bias, permuted [h][mi][nj][c][g][r]

// ---------------- prep kernels ----------------

__global__ void prep0(const float* __restrict__ qw, const float* __restrict__ prw,
                      const float* __restrict__ qbias, const float* __restrict__ vbias,
                      const float* __restrict__ ls, char* __restrict__ ws) {
    int t = blockIdx.x * 256 + threadIdx.x;
    f16* wq = (f16*)(ws + WQ_OFF);
    f16* pw = (f16*)(ws + PW_OFF);
    if (t < 196608) wq[t] = (f16)qw[t];
    else            pw[t - 196608] = (f16)prw[t - 196608];
    if (t < 768) {
        float b = t < 256 ? qbias[t] : (t < 512 ? 0.f : vbias[t - 512]);
        ((float*)(ws + QB_OFF))[t] = b;
    }
    if (t < 8) ((float*)(ws + SC_OFF))[t] = expf(fminf(ls[t], 4.6051701859880914f));
}

__device__ __forceinline__ float norm_coord(int u) { // u in 0..14
    float v = (float)(u - 7) * (8.0f / 7.0f);
    float s = (v > 0.f) ? 1.f : ((v < 0.f) ? -1.f : 0.f);
    return s * log2f(fabsf(v) + 1.f) * (1.f / 3.f);
}

__global__ void prep1(const float* __restrict__ w1, const float* __restrict__ b1,
                      const float* __restrict__ w2, char* __restrict__ ws) {
    int t = blockIdx.x * 256 + threadIdx.x; // 1800 used
    if (t >= 1800) return;
    int p = t >> 3, h = t & 7;
    float ta = norm_coord(p / 15);
    float tb = norm_coord(p % 15);
    float acc = 0.f;
    for (int j = 0; j < 512; ++j) {
        float hv = fmaf(w1[2 * j], ta, fmaf(w1[2 * j + 1], tb, b1[j]));
        acc = fmaf(fmaxf(hv, 0.f), w2[h * 512 + j], acc);
    }
    ((float*)(ws + TBL_OFF))[p * 8 + h] = acc;
}

__global__ void prep2(char* __restrict__ ws) {
    int t = blockIdx.x * 256 + threadIdx.x; // 32768 = 8*64*64
    int h = t >> 12, i = (t >> 6) & 63, j = t & 63;
    int ri = ((i >> 3) - (j >> 3) + 7) * 15 + ((i & 7) - (j & 7) + 7);
    float bv = ((const float*)(ws + TBL_OFF))[ri * 8 + h];
    float sg = 1.f / (1.f + expf(-bv));
    float sch = ((const float*)(ws + SC_OFF))[h];
    // +14.0: scale all e by 2^14 so the f16-rounded P stays in normal range;
    // the factor cancels exactly in O * 1/rowsum (rowsum uses the same scaled e).
    float val = (16.f * sg - sch - 16.f) * L2E + 14.0f;
    // permuted layout [h][mi][nj][c][g][r] for coalesced f32x4-over-r loads
    int mi = i >> 4, g = (i >> 2) & 3, r = i & 3;
    int nj = j >> 4, c = j & 15;
    int off = h * 4096 + mi * 1024 + nj * 256 + c * 16 + g * 4 + r;
    ((float*)(ws + BB_OFF))[off] = val;
}

// ---------------- fused main kernel ----------------
// 1 block = 1 window, 256 threads = 4 waves; wave w runs heads w and w+4.
// LDS (53248 B):
//   [0, 32768)      : x f16 [64][256] swz -> O f16 (same region)
//   [32768, 53248)  : per-wave 5120 B scratch (V^T -> Qhat -> Khat -> P per head);
//                     after attention: 16 KB shared f32 staging for proj chunks
// Occupancy model (R1..R6): pool = 512 regs/SIMD, alloc = archVGPR + AGPR.
// R6: 124 + 64(proj pacc) = 188 -> 2 waves/SIMD. This round caps AGPR at 32
// (attention oo; proj done in 4 chunks of pacc[4]=16) and pins the allocation
// with __launch_bounds__(256,3): total <= 170 -> 3 waves/SIMD = 3 blocks/CU.
#define SWZ(row) (((row) & 7) << 4)
#define LGKM0() asm volatile("s_waitcnt lgkmcnt(0)" ::: "memory")

__global__ __launch_bounds__(256, 3)
void swin_fused(const float* __restrict__ x, const f16* __restrict__ wq,
                const f16* __restrict__ pw, const float* __restrict__ qb,
                const float* __restrict__ sc, const float* __restrict__ bb2,
                const float* __restrict__ pb, float* __restrict__ out) {
    extern __shared__ char lds[];
    const int tid = threadIdx.x;      // 0..255
    const int lane = tid & 63;
    const int w = tid >> 6;           // wave 0..3
    const int g = lane >> 4;
    const int c = lane & 15;
    const int win = blockIdx.x;
    char* scr = lds + 32768 + w * 5120;
    char* stg = lds + 32768;          // 16 KB shared staging (proj epilogue)

    // ---- phase 0: stage x -> LDS fp16 (swizzled) ----
    const float* xw = x + (size_t)win * 16384;
    #pragma unroll
    for (int it = 0; it < 16; ++it) {
        int e4 = tid + it * 256;
        float4 v = ((const float4*)xw)[e4];
        int eidx = e4 * 4;
        int row = eidx >> 8, col = eidx & 255;
        f16x4 h4 = {(f16)v.x, (f16)v.y, (f16)v.z, (f16)v.w};
        int off = ((row << 9) + (col << 1)) ^ SWZ(row);
        *(f16x4*)(lds + off) = h4;
    }
    __syncthreads(); // (1)

    f16x4 po[4][2]; // head-0 packed O (carried through head-1): [mi][dt] x 4 r-vals

    for (int hh = 0; hh < 2; ++hh) {
        const int h = w + hh * 4;

        // ---- V GEMM (head h, cols 512+32h..+32) -> V^T scratch -> vf regs ----
        f16x8 vf[2][2]; // [dt][kt]
        {
            f32x4 acc[2][4] = {};
            #pragma unroll 2
            for (int kk = 0; kk < 8; ++kk) {
                int kb = kk * 32 + g * 8;
                f16x8 a[4];
                #pragma unroll
                for (int mi = 0; mi < 4; ++mi) {
                    int row = mi * 16 + c;
                    int off = ((row << 9) + (kb << 1)) ^ SWZ(row);
                    a[mi] = *(const f16x8*)(lds + off);
                }
                #pragma unroll
                for (int t = 0; t < 2; ++t) {
                    f16x8 b = *(const f16x8*)(wq + (size_t)(512 + h * 32 + t * 16 + c) * 256 + kb);
                    #pragma unroll
                    for (int mi = 0; mi < 4; ++mi)
                        acc[t][mi] = __builtin_amdgcn_mfma_f32_16x16x32_f16(a[mi], b, acc[t][mi], 0, 0, 0);
                }
            }
            #pragma unroll
            for (int t = 0; t < 2; ++t) {
                float bias = qb[512 + h * 32 + t * 16 + c];
                #pragma unroll
                for (int mi = 0; mi < 4; ++mi) {
                    f16x4 hv;
                    #pragma unroll
                    for (int r = 0; r < 4; ++r) hv[r] = (f16)(acc[t][mi][r] + bias);
                    // V^T [d=32][token=64], row stride 144 B
                    int off = (t * 16 + c) * 144 + (mi * 16 + g * 4) * 2;
                    *(f16x4*)(scr + off) = hv;
                }
            }
        }
        LGKM0();
        #pragma unroll
        for (int dt = 0; dt < 2; ++dt)
            #pragma unroll
            for (int kt = 0; kt < 2; ++kt)
                vf[dt][kt] = *(const f16x8*)(scr + (dt * 16 + c) * 144 + kt * 64 + g * 16);
        LGKM0();

        // ---- Q GEMM pass -> normalize -> Qhat scratch -> qf regs ----
        f16x8 qf[4], kf[4];
        {
            f32x4 aq[2][4] = {};
            #pragma unroll 2
            for (int kk = 0; kk < 8; ++kk) {
                int kb = kk * 32 + g * 8;
                f16x8 a[4];
                #pragma unroll
                for (int mi = 0; mi < 4; ++mi) {
                    int row = mi * 16 + c;
                    int off = ((row << 9) + (kb << 1)) ^ SWZ(row);
                    a[mi] = *(const f16x8*)(lds + off);
                }
                #pragma unroll
                for (int t = 0; t < 2; ++t) {
                    f16x8 bq = *(const f16x8*)(wq + (size_t)(h * 32 + t * 16 + c) * 256 + kb);
                    #pragma unroll
                    for (int mi = 0; mi < 4; ++mi)
                        aq[t][mi] = __builtin_amdgcn_mfma_f32_16x16x32_f16(a[mi], bq, aq[t][mi], 0, 0, 0);
                }
            }
            #pragma unroll
            for (int t = 0; t < 2; ++t) {
                float bias = qb[h * 32 + t * 16 + c];
                #pragma unroll
                for (int mi = 0; mi < 4; ++mi)
                    #pragma unroll
                    for (int r = 0; r < 4; ++r) aq[t][mi][r] += bias;
            }
            #pragma unroll
            for (int mi = 0; mi < 4; ++mi) {
                #pragma unroll
                for (int r = 0; r < 4; ++r) {
                    float pq = aq[0][mi][r] * aq[0][mi][r] + aq[1][mi][r] * aq[1][mi][r];
                    pq += __shfl_xor(pq, 1); pq += __shfl_xor(pq, 2);
                    pq += __shfl_xor(pq, 4); pq += __shfl_xor(pq, 8);
                    float rq = __builtin_amdgcn_rsqf(fmaxf(pq, 1e-24f));
                    aq[0][mi][r] *= rq; aq[1][mi][r] *= rq;
                }
            }
            #pragma unroll
            for (int t = 0; t < 2; ++t)
                #pragma unroll
                for (int mi = 0; mi < 4; ++mi)
                    #pragma unroll
                    for (int r = 0; r < 4; ++r) {
                        int off = (mi * 16 + g * 4 + r) * 80 + (t * 16 + c) * 2;
                        *(f16*)(scr + off) = (f16)aq[t][mi][r];
                    }
            LGKM0();
            #pragma unroll
            for (int mi = 0; mi < 4; ++mi)
                qf[mi] = *(const f16x8*)(scr + (mi * 16 + c) * 80 + g * 16);
            LGKM0();
        }
        // ---- K GEMM pass (k bias zero) -> Khat -> kf regs ----
        {
            f32x4 ak[2][4] = {};
            #pragma unroll 2
            for (int kk = 0; kk < 8; ++kk) {
                int kb = kk * 32 + g * 8;
                f16x8 a[4];
                #pragma unroll
                for (int mi = 0; mi < 4; ++mi) {
                    int row = mi * 16 + c;
                    int off = ((row << 9) + (kb << 1)) ^ SWZ(row);
                    a[mi] = *(const f16x8*)(lds + off);
                }
                #pragma unroll
                for (int t = 0; t < 2; ++t) {
                    f16x8 bk = *(const f16x8*)(wq + (size_t)(256 + h * 32 + t * 16 + c) * 256 + kb);
                    #pragma unroll
                    for (int mi = 0; mi < 4; ++mi)
                        ak[t][mi] = __builtin_amdgcn_mfma_f32_16x16x32_f16(a[mi], bk, ak[t][mi], 0, 0, 0);
                }
            }
            #pragma unroll
            for (int mi = 0; mi < 4; ++mi) {
                #pragma unroll
                for (int r = 0; r < 4; ++r) {
                    float pk = ak[0][mi][r] * ak[0][mi][r] + ak[1][mi][r] * ak[1][mi][r];
                    pk += __shfl_xor(pk, 1); pk += __shfl_xor(pk, 2);
                    pk += __shfl_xor(pk, 4); pk += __shfl_xor(pk, 8);
                    float rk = __builtin_amdgcn_rsqf(fmaxf(pk, 1e-24f));
                    ak[0][mi][r] *= rk; ak[1][mi][r] *= rk;
                }
            }
            #pragma unroll
            for (int t = 0; t < 2; ++t)
                #pragma unroll
                for (int mi = 0; mi < 4; ++mi)
                    #pragma unroll
                    for (int r = 0; r < 4; ++r) {
                        int off = (mi * 16 + g * 4 + r) * 80 + (t * 16 + c) * 2;
                        *(f16*)(scr + off) = (f16)ak[t][mi][r];
                    }
            LGKM0();
            #pragma unroll
            for (int nj = 0; nj < 4; ++nj)
                kf[nj] = *(const f16x8*)(scr + (nj * 16 + c) * 80 + g * 16);
            LGKM0();
        }

        if (hh == 1) {
            // all x-reads block-wide are complete -> x-region becomes O-region
            __syncthreads(); // (2)
            const int h0 = w;
            #pragma unroll
            for (int mi = 0; mi < 4; ++mi)
                #pragma unroll
                for (int dt = 0; dt < 2; ++dt)
                    #pragma unroll
                    for (int r = 0; r < 4; ++r) {
                        int row = mi * 16 + g * 4 + r;
                        int col = h0 * 32 + dt * 16 + c;
                        int off = ((row << 9) + (col << 1)) ^ SWZ(row);
                        *(f16*)(lds + off) = po[mi][dt][r];
                    }
        }

        // ---- QK quarters -> exp (+rowsum) -> P scratch, interleaved PV ----
        const float scl2e = sc[h] * L2E;
        const float* bbw = bb2 + h * 4096;
        f32x4 oo[4][2] = {};  // [mo][dt]  (32 AGPR = kernel max)
        f32x4 rs[4] = {};     // rowsum partials per (mi, r)
        #pragma unroll
        for (int nj = 0; nj < 4; ++nj) {
            #pragma unroll
            for (int mi = 0; mi < 4; ++mi) {
                f32x4 z = {};
                f32x4 s = __builtin_amdgcn_mfma_f32_16x16x32_f16(qf[mi], kf[nj], z, 0, 0, 0);
                f32x4 bb4 = *(const f32x4*)(bbw + mi * 1024 + nj * 256 + c * 16 + g * 4);
                #pragma unroll
                for (int r = 0; r < 4; ++r) {
                    float e = exp2f(fmaf(s[r], scl2e, bb4[r]));
                    rs[mi][r] += e;
                    int off = (mi * 16 + g * 4 + r) * 80 + (((nj & 1) * 16 + c) << 1);
                    *(f16*)(scr + off) = (f16)e;
                }
            }
            if (nj & 1) {
                const int kt = nj >> 1;
                LGKM0();
                f16x8 pa[4];
                #pragma unroll
                for (int mo = 0; mo < 4; ++mo)
                    pa[mo] = *(const f16x8*)(scr + (mo * 16 + c) * 80 + g * 16);
                LGKM0();
                #pragma unroll
                for (int mo = 0; mo < 4; ++mo)
                    #pragma unroll
                    for (int dt = 0; dt < 2; ++dt)
                        oo[mo][dt] = __builtin_amdgcn_mfma_f32_16x16x32_f16(pa[mo], vf[dt][kt], oo[mo][dt], 0, 0, 0);
            }
        }
        // rowsum reduce (over the 16 c-lanes) -> reciprocal in place; normalize O
        #pragma unroll
        for (int mi = 0; mi < 4; ++mi)
            #pragma unroll
            for (int r = 0; r < 4; ++r) {
                float t = rs[mi][r];
                t += __shfl_xor(t, 1); t += __shfl_xor(t, 2);
                t += __shfl_xor(t, 4); t += __shfl_xor(t, 8);
                float ri = __builtin_amdgcn_rcpf(t);
                oo[mi][0][r] *= ri;
                oo[mi][1][r] *= ri;
            }
        if (hh == 0) {
            #pragma unroll
            for (int mi = 0; mi < 4; ++mi)
                #pragma unroll
                for (int dt = 0; dt < 2; ++dt)
                    #pragma unroll
                    for (int r = 0; r < 4; ++r)
                        po[mi][dt][r] = (f16)oo[mi][dt][r];
        } else {
            #pragma unroll
            for (int mi = 0; mi < 4; ++mi)
                #pragma unroll
                for (int dt = 0; dt < 2; ++dt)
                    #pragma unroll
                    for (int r = 0; r < 4; ++r) {
                        int row = mi * 16 + g * 4 + r;
                        int col = h * 32 + dt * 16 + c;
                        int off = ((row << 9) + (col << 1)) ^ SWZ(row);
                        *(f16*)(lds + off) = (f16)oo[mi][dt][r];
                    }
        }
    }
    __syncthreads(); // (3) O complete -> proj may read; scratch now dead

    // ---- proj GEMM in 4 row-chunks of 16 (pacc[4] = 16 AGPR), staged via
    //      the 16 KB scratch region, full-line float4 stores ----
    float pbias[4];
    #pragma unroll
    for (int nt = 0; nt < 4; ++nt) pbias[nt] = pb[w * 64 + nt * 16 + c];
    for (int cc = 0; cc < 4; ++cc) {
        f32x4 pacc[4] = {}; // [nt]
        #pragma unroll 2
        for (int kk = 0; kk < 8; ++kk) {
            int kb = kk * 32 + g * 8;
            int row = cc * 16 + c;
            int off = ((row << 9) + (kb << 1)) ^ SWZ(row);
            f16x8 a = *(const f16x8*)(lds + off);
            #pragma unroll
            for (int nt = 0; nt < 4; ++nt) {
                f16x8 b = *(const f16x8*)(pw + (size_t)(w * 64 + nt * 16 + c) * 256 + kb);
                pacc[nt] = __builtin_amdgcn_mfma_f32_16x16x32_f16(a, b, pacc[nt], 0, 0, 0);
            }
        }
        __syncthreads(); // staging region free (prev chunk's store-reads done)
        #pragma unroll
        for (int nt = 0; nt < 4; ++nt)
            #pragma unroll
            for (int r = 0; r < 4; ++r) {
                int row = g * 4 + r;                 // 0..15 within chunk
                int col = w * 64 + nt * 16 + c;
                int off = (row * 1024 + col * 4) ^ ((row & 7) << 4);
                *(float*)(stg + off) = pacc[nt][r] + pbias[nt];
            }
        __syncthreads(); // staging visible
        float4* out4 = (float4*)(out + (size_t)win * 16384 + cc * 4096);
        #pragma unroll
        for (int it = 0; it < 4; ++it) {
            int e4 = it * 256 + tid;                 // 1024 float4 per chunk
            int off = (e4 * 16) ^ (((e4 >> 6) & 7) << 4);
            out4[e4] = *(const float4*)(stg + off);
        }
    }
}

// ---------------- launch ----------------

extern "C" void kernel_launch(void* const* d_in, const int* in_sizes, int n_in,
                              void* d_out, int out_size, void* d_ws, size_t ws_size,
                              hipStream_t stream) {
    (void)in_sizes; (void)n_in; (void)out_size; (void)ws_size;
    const float* x   = (const float*)d_in[0];
    const float* qw  = (const float*)d_in[1];
    const float* qb_ = (const float*)d_in[2];
    const float* vb_ = (const float*)d_in[3];
    const float* ls  = (const float*)d_in[4];
    const float* w1  = (const float*)d_in[5];
    const float* b1  = (const float*)d_in[6];
    const float* w2  = (const float*)d_in[7];
    const float* prw = (const float*)d_in[8];
    const float* pb  = (const float*)d_in[9];
    float* out = (float*)d_out;
    char* ws = (char*)d_ws;

    prep0<<<1024, 256, 0, stream>>>(qw, prw, qb_, vb_, ls, ws);
    prep1<<<8, 256, 0, stream>>>(w1, b1, w2, ws);
    prep2<<<128, 256, 0, stream>>>(ws);

    (void)hipFuncSetAttribute((const void*)swin_fused,
                              hipFuncAttributeMaxDynamicSharedMemorySize, 53248);
    swin_fused<<<8192, 256, 53248, stream>>>(
        x,
        (const f16*)(ws + WQ_OFF), (const f16*)(ws + PW_OFF),
        (const float*)(ws + QB_OFF), (const float*)(ws + SC_OFF),
        (const float*)(ws + BB_OFF), pb, out);
}

// Round 8
// 1068.686 us; speedup vs baseline: 1.1791x; 1.1791x over previous
//
#include <hip/hip_runtime.h>
#include <hip/hip_fp16.h>

typedef _Float16 f16;
typedef _Float16 f16x8 __attribute__((ext_vector_type(8)));
typedef _Float16 f16x4 __attribute__((ext_vector_type(4)));
typedef float f32x4 __attribute__((ext_vector_type(4)));

#define L2E 1.4426950408889634f

// workspace layout (bytes)
#define WQ_OFF   0         // 768*256 f16   qkv weight, row-major [n][k]
#define PW_OFF   393216    // 256*256 f16   proj weight, row-major [n][k]
#define QB_OFF   524288    // 768 f32       concat qkv bias (k-bias = 0)
#define SC_OFF   527360    // 8 f32         exp(min(logit_scale, ln100))
#define TBL_OFF  527616    // 225*8 f32     cpb mlp table
#define BB_OFF   535040    // 32768 f32     folded bias, permuted [h][mi][nj][c][g][r]

// ---------------- prep kernels ----------------

__global__ void prep0(const float* __restrict__ qw, const float* __restrict__ prw,
                      const float* __restrict__ qbias, const float* __restrict__ vbias,
                      const float* __restrict__ ls, char* __restrict__ ws) {
    int t = blockIdx.x * 256 + threadIdx.x;
    f16* wq = (f16*)(ws + WQ_OFF);
    f16* pw = (f16*)(ws + PW_OFF);
    if (t < 196608) wq[t] = (f16)qw[t];
    else            pw[t - 196608] = (f16)prw[t - 196608];
    if (t < 768) {
        float b = t < 256 ? qbias[t] : (t < 512 ? 0.f : vbias[t - 512]);
        ((float*)(ws + QB_OFF))[t] = b;
    }
    if (t < 8) ((float*)(ws + SC_OFF))[t] = expf(fminf(ls[t], 4.6051701859880914f));
}

__device__ __forceinline__ float norm_coord(int u) { // u in 0..14
    float v = (float)(u - 7) * (8.0f / 7.0f);
    float s = (v > 0.f) ? 1.f : ((v < 0.f) ? -1.f : 0.f);
    return s * log2f(fabsf(v) + 1.f) * (1.f / 3.f);
}

__global__ void prep1(const float* __restrict__ w1, const float* __restrict__ b1,
                      const float* __restrict__ w2, char* __restrict__ ws) {
    int t = blockIdx.x * 256 + threadIdx.x; // 1800 used
    if (t >= 1800) return;
    int p = t >> 3, h = t & 7;
    float ta = norm_coord(p / 15);
    float tb = norm_coord(p % 15);
    float acc = 0.f;
    for (int j = 0; j < 512; ++j) {
        float hv = fmaf(w1[2 * j], ta, fmaf(w1[2 * j + 1], tb, b1[j]));
        acc = fmaf(fmaxf(hv, 0.f), w2[h * 512 + j], acc);
    }
    ((float*)(ws + TBL_OFF))[p * 8 + h] = acc;
}

__global__ void prep2(char* __restrict__ ws) {
    int t = blockIdx.x * 256 + threadIdx.x; // 32768 = 8*64*64
    int h = t >> 12, i = (t >> 6) & 63, j = t & 63;
    int ri = ((i >> 3) - (j >> 3) + 7) * 15 + ((i & 7) - (j & 7) + 7);
    float bv = ((const float*)(ws + TBL_OFF))[ri * 8 + h];
    float sg = 1.f / (1.f + expf(-bv));
    float sch = ((const float*)(ws + SC_OFF))[h];
    // +14.0: scale all e by 2^14 so the f16-rounded P stays in normal range;
    // the factor cancels exactly in O * 1/rowsum (rowsum uses the same scaled e).
    float val = (16.f * sg - sch - 16.f) * L2E + 14.0f;
    // permuted layout [h][mi][nj][c][g][r] for coalesced f32x4-over-r loads
    int mi = i >> 4, g = (i >> 2) & 3, r = i & 3;
    int nj = j >> 4, c = j & 15;
    int off = h * 4096 + mi * 1024 + nj * 256 + c * 16 + g * 4 + r;
    ((float*)(ws + BB_OFF))[off] = val;
}

// ---------------- fused main kernel ----------------
// 1 block = 1 window, 256 threads = 4 waves; wave w runs heads w and w+4.
// LDS (53248 B -> 3 blocks/CU, 159.7 KB of 160 KB):
//   [0, 32768)      : x f16 [64][256] swz -> O f16 (same region)
//   [32768, 53248)  : per-wave 5120 B scratch (V^T -> Qhat -> Khat -> P per head);
//                     after attention: 16 KB shared f32 staging for proj chunks
// Register model (R1..R7): pool = 512/SIMD, alloc = archVGPR + AGPR.
//  - TIGHT bounds ((512,4), (256,3), wpe(4,4)) make the allocator split the
//    cap ~evenly arch/AGPR (R7: cap 170 -> arch 84) -> spills (live ~120).
//  - LOOSE bound (256,2) allocates naturally: arch ~124 + AGPR 32 = ~156
//    <= 170 -> hardware runs 3 waves/SIMD anyway; LDS also allows 3 blocks.
// AGPR capped at 32 by R7's restructuring: attention oo[4][2]=32; proj done
// in 4 row-chunks with pacc[4]=16.
#define SWZ(row) (((row) & 7) << 4)
#define LGKM0() asm volatile("s_waitcnt lgkmcnt(0)" ::: "memory")

__global__ __launch_bounds__(256, 2)
void swin_fused(const float* __restrict__ x, const f16* __restrict__ wq,
                const f16* __restrict__ pw, const float* __restrict__ qb,
                const float* __restrict__ sc, const float* __restrict__ bb2,
                const float* __restrict__ pb, float* __restrict__ out) {
    extern __shared__ char lds[];
    const int tid = threadIdx.x;      // 0..255
    const int lane = tid & 63;
    const int w = tid >> 6;           // wave 0..3
    const int g = lane >> 4;
    const int c = lane & 15;
    const int win = blockIdx.x;
    char* scr = lds + 32768 + w * 5120;
    char* stg = lds + 32768;          // 16 KB shared staging (proj epilogue)

    // ---- phase 0: stage x -> LDS fp16 (swizzled) ----
    const float* xw = x + (size_t)win * 16384;
    #pragma unroll
    for (int it = 0; it < 16; ++it) {
        int e4 = tid + it * 256;
        float4 v = ((const float4*)xw)[e4];
        int eidx = e4 * 4;
        int row = eidx >> 8, col = eidx & 255;
        f16x4 h4 = {(f16)v.x, (f16)v.y, (f16)v.z, (f16)v.w};
        int off = ((row << 9) + (col << 1)) ^ SWZ(row);
        *(f16x4*)(lds + off) = h4;
    }
    __syncthreads(); // (1)

    f16x4 po[4][2]; // head-0 packed O (carried through head-1): [mi][dt] x 4 r-vals

    for (int hh = 0; hh < 2; ++hh) {
        const int h = w + hh * 4;

        // ---- V GEMM (head h, cols 512+32h..+32) -> V^T scratch -> vf regs ----
        f16x8 vf[2][2]; // [dt][kt]
        {
            f32x4 acc[2][4] = {};
            #pragma unroll 2
            for (int kk = 0; kk < 8; ++kk) {
                int kb = kk * 32 + g * 8;
                f16x8 a[4];
                #pragma unroll
                for (int mi = 0; mi < 4; ++mi) {
                    int row = mi * 16 + c;
                    int off = ((row << 9) + (kb << 1)) ^ SWZ(row);
                    a[mi] = *(const f16x8*)(lds + off);
                }
                #pragma unroll
                for (int t = 0; t < 2; ++t) {
                    f16x8 b = *(const f16x8*)(wq + (size_t)(512 + h * 32 + t * 16 + c) * 256 + kb);
                    #pragma unroll
                    for (int mi = 0; mi < 4; ++mi)
                        acc[t][mi] = __builtin_amdgcn_mfma_f32_16x16x32_f16(a[mi], b, acc[t][mi], 0, 0, 0);
                }
            }
            #pragma unroll
            for (int t = 0; t < 2; ++t) {
                float bias = qb[512 + h * 32 + t * 16 + c];
                #pragma unroll
                for (int mi = 0; mi < 4; ++mi) {
                    f16x4 hv;
                    #pragma unroll
                    for (int r = 0; r < 4; ++r) hv[r] = (f16)(acc[t][mi][r] + bias);
                    // V^T [d=32][token=64], row stride 144 B
                    int off = (t * 16 + c) * 144 + (mi * 16 + g * 4) * 2;
                    *(f16x4*)(scr + off) = hv;
                }
            }
        }
        LGKM0();
        #pragma unroll
        for (int dt = 0; dt < 2; ++dt)
            #pragma unroll
            for (int kt = 0; kt < 2; ++kt)
                vf[dt][kt] = *(const f16x8*)(scr + (dt * 16 + c) * 144 + kt * 64 + g * 16);
        LGKM0();

        // ---- Q GEMM pass -> normalize -> Qhat scratch -> qf regs ----
        f16x8 qf[4], kf[4];
        {
            f32x4 aq[2][4] = {};
            #pragma unroll 2
            for (int kk = 0; kk < 8; ++kk) {
                int kb = kk * 32 + g * 8;
                f16x8 a[4];
                #pragma unroll
                for (int mi = 0; mi < 4; ++mi) {
                    int row = mi * 16 + c;
                    int off = ((row << 9) + (kb << 1)) ^ SWZ(row);
                    a[mi] = *(const f16x8*)(lds + off);
                }
                #pragma unroll
                for (int t = 0; t < 2; ++t) {
                    f16x8 bq = *(const f16x8*)(wq + (size_t)(h * 32 + t * 16 + c) * 256 + kb);
                    #pragma unroll
                    for (int mi = 0; mi < 4; ++mi)
                        aq[t][mi] = __builtin_amdgcn_mfma_f32_16x16x32_f16(a[mi], bq, aq[t][mi], 0, 0, 0);
                }
            }
            #pragma unroll
            for (int t = 0; t < 2; ++t) {
                float bias = qb[h * 32 + t * 16 + c];
                #pragma unroll
                for (int mi = 0; mi < 4; ++mi)
                    #pragma unroll
                    for (int r = 0; r < 4; ++r) aq[t][mi][r] += bias;
            }
            #pragma unroll
            for (int mi = 0; mi < 4; ++mi) {
                #pragma unroll
                for (int r = 0; r < 4; ++r) {
                    float pq = aq[0][mi][r] * aq[0][mi][r] + aq[1][mi][r] * aq[1][mi][r];
                    pq += __shfl_xor(pq, 1); pq += __shfl_xor(pq, 2);
                    pq += __shfl_xor(pq, 4); pq += __shfl_xor(pq, 8);
                    float rq = __builtin_amdgcn_rsqf(fmaxf(pq, 1e-24f));
                    aq[0][mi][r] *= rq; aq[1][mi][r] *= rq;
                }
            }
            #pragma unroll
            for (int t = 0; t < 2; ++t)
                #pragma unroll
                for (int mi = 0; mi < 4; ++mi)
                    #pragma unroll
                    for (int r = 0; r < 4; ++r) {
                        int off = (mi * 16 + g * 4 + r) * 80 + (t * 16 + c) * 2;
                        *(f16*)(scr + off) = (f16)aq[t][mi][r];
                    }
            LGKM0();
            #pragma unroll
            for (int mi = 0; mi < 4; ++mi)
                qf[mi] = *(const f16x8*)(scr + (mi * 16 + c) * 80 + g * 16);
            LGKM0();
        }
        // ---- K GEMM pass (k bias zero) -> Khat -> kf regs ----
        {
            f32x4 ak[2][4] = {};
            #pragma unroll 2
            for (int kk = 0; kk < 8; ++kk) {
                int kb = kk * 32 + g * 8;
                f16x8 a[4];
                #pragma unroll
                for (int mi = 0; mi < 4; ++mi) {
                    int row = mi * 16 + c;
                    int off = ((row << 9) + (kb << 1)) ^ SWZ(row);
                    a[mi] = *(const f16x8*)(lds + off);
                }
                #pragma unroll
                for (int t = 0; t < 2; ++t) {
                    f16x8 bk = *(const f16x8*)(wq + (size_t)(256 + h * 32 + t * 16 + c) * 256 + kb);
                    #pragma unroll
                    for (int mi = 0; mi < 4; ++mi)
                        ak[t][mi] = __builtin_amdgcn_mfma_f32_16x16x32_f16(a[mi], bk, ak[t][mi], 0, 0, 0);
                }
            }
            #pragma unroll
            for (int mi = 0; mi < 4; ++mi) {
                #pragma unroll
                for (int r = 0; r < 4; ++r) {
                    float pk = ak[0][mi][r] * ak[0][mi][r] + ak[1][mi][r] * ak[1][mi][r];
                    pk += __shfl_xor(pk, 1); pk += __shfl_xor(pk, 2);
                    pk += __shfl_xor(pk, 4); pk += __shfl_xor(pk, 8);
                    float rk = __builtin_amdgcn_rsqf(fmaxf(pk, 1e-24f));
                    ak[0][mi][r] *= rk; ak[1][mi][r] *= rk;
                }
            }
            #pragma unroll
            for (int t = 0; t < 2; ++t)
                #pragma unroll
                for (int mi = 0; mi < 4; ++mi)
                    #pragma unroll
                    for (int r = 0; r < 4; ++r) {
                        int off = (mi * 16 + g * 4 + r) * 80 + (t * 16 + c) * 2;
                        *(f16*)(scr + off) = (f16)ak[t][mi][r];
                    }
            LGKM0();
            #pragma unroll
            for (int nj = 0; nj < 4; ++nj)
                kf[nj] = *(const f16x8*)(scr + (nj * 16 + c) * 80 + g * 16);
            LGKM0();
        }

        if (hh == 1) {
            // all x-reads block-wide are complete -> x-region becomes O-region
            __syncthreads(); // (2)
            const int h0 = w;
            #pragma unroll
            for (int mi = 0; mi < 4; ++mi)
                #pragma unroll
                for (int dt = 0; dt < 2; ++dt)
                    #pragma unroll
                    for (int r = 0; r < 4; ++r) {
                        int row = mi * 16 + g * 4 + r;
                        int col = h0 * 32 + dt * 16 + c;
                        int off = ((row << 9) + (col << 1)) ^ SWZ(row);
                        *(f16*)(lds + off) = po[mi][dt][r];
                    }
        }

        // ---- QK quarters -> exp (+rowsum) -> P scratch, interleaved PV ----
        const float scl2e = sc[h] * L2E;
        const float* bbw = bb2 + h * 4096;
        f32x4 oo[4][2] = {};  // [mo][dt]  (32 AGPR = kernel max)
        f32x4 rs[4] = {};     // rowsum partials per (mi, r)
        #pragma unroll
        for (int nj = 0; nj < 4; ++nj) {
            #pragma unroll
            for (int mi = 0; mi < 4; ++mi) {
                f32x4 z = {};
                f32x4 s = __builtin_amdgcn_mfma_f32_16x16x32_f16(qf[mi], kf[nj], z, 0, 0, 0);
                f32x4 bb4 = *(const f32x4*)(bbw + mi * 1024 + nj * 256 + c * 16 + g * 4);
                #pragma unroll
                for (int r = 0; r < 4; ++r) {
                    float e = exp2f(fmaf(s[r], scl2e, bb4[r]));
                    rs[mi][r] += e;
                    int off = (mi * 16 + g * 4 + r) * 80 + (((nj & 1) * 16 + c) << 1);
                    *(f16*)(scr + off) = (f16)e;
                }
            }
            if (nj & 1) {
                const int kt = nj >> 1;
                LGKM0();
                f16x8 pa[4];
                #pragma unroll
                for (int mo = 0; mo < 4; ++mo)
                    pa[mo] = *(const f16x8*)(scr + (mo * 16 + c) * 80 + g * 16);
                LGKM0();
                #pragma unroll
                for (int mo = 0; mo < 4; ++mo)
                    #pragma unroll
                    for (int dt = 0; dt < 2; ++dt)
                        oo[mo][dt] = __builtin_amdgcn_mfma_f32_16x16x32_f16(pa[mo], vf[dt][kt], oo[mo][dt], 0, 0, 0);
            }
        }
        // rowsum reduce (over the 16 c-lanes) -> reciprocal in place; normalize O
        #pragma unroll
        for (int mi = 0; mi < 4; ++mi)
            #pragma unroll
            for (int r = 0; r < 4; ++r) {
                float t = rs[mi][r];
                t += __shfl_xor(t, 1); t += __shfl_xor(t, 2);
                t += __shfl_xor(t, 4); t += __shfl_xor(t, 8);
                float ri = __builtin_amdgcn_rcpf(t);
                oo[mi][0][r] *= ri;
                oo[mi][1][r] *= ri;
            }
        if (hh == 0) {
            #pragma unroll
            for (int mi = 0; mi < 4; ++mi)
                #pragma unroll
                for (int dt = 0; dt < 2; ++dt)
                    #pragma unroll
                    for (int r = 0; r < 4; ++r)
                        po[mi][dt][r] = (f16)oo[mi][dt][r];
        } else {
            #pragma unroll
            for (int mi = 0; mi < 4; ++mi)
                #pragma unroll
                for (int dt = 0; dt < 2; ++dt)
                    #pragma unroll
                    for (int r = 0; r < 4; ++r) {
                        int row = mi * 16 + g * 4 + r;
                        int col = h * 32 + dt * 16 + c;
                        int off = ((row << 9) + (col << 1)) ^ SWZ(row);
                        *(f16*)(lds + off) = (f16)oo[mi][dt][r];
                    }
        }
    }
    __syncthreads(); // (3) O complete -> proj may read; scratch now dead

    // ---- proj GEMM in 4 row-chunks of 16 (pacc[4] = 16 AGPR), staged via
    //      the 16 KB scratch region, full-line float4 stores ----
    float pbias[4];
    #pragma unroll
    for (int nt = 0; nt < 4; ++nt) pbias[nt] = pb[w * 64 + nt * 16 + c];
    for (int cc = 0; cc < 4; ++cc) {
        f32x4 pacc[4] = {}; // [nt]
        #pragma unroll 2
        for (int kk = 0; kk < 8; ++kk) {
            int kb = kk * 32 + g * 8;
            int row = cc * 16 + c;
            int off = ((row << 9) + (kb << 1)) ^ SWZ(row);
            f16x8 a = *(const f16x8*)(lds + off);
            #pragma unroll
            for (int nt = 0; nt < 4; ++nt) {
                f16x8 b = *(const f16x8*)(pw + (size_t)(w * 64 + nt * 16 + c) * 256 + kb);
                pacc[nt] = __builtin_amdgcn_mfma_f32_16x16x32_f16(a, b, pacc[nt], 0, 0, 0);
            }
        }
        __syncthreads(); // staging region free (prev chunk's store-reads done)
        #pragma unroll
        for (int nt = 0; nt < 4; ++nt)
            #pragma unroll
            for (int r = 0; r < 4; ++r) {
                int row = g * 4 + r;                 // 0..15 within chunk
                int col = w * 64 + nt * 16 + c;
                int off = (row * 1024 + col * 4) ^ ((row & 7) << 4);
                *(float*)(stg + off) = pacc[nt][r] + pbias[nt];
            }
        __syncthreads(); // staging visible
        float4* out4 = (float4*)(out + (size_t)win * 16384 + cc * 4096);
        #pragma unroll
        for (int it = 0; it < 4; ++it) {
            int e4 = it * 256 + tid;                 // 1024 float4 per chunk
            int off = (e4 * 16) ^ (((e4 >> 6) & 7) << 4);
            out4[e4] = *(const float4*)(stg + off);
        }
    }
}

// ---------------- launch ----------------

extern "C" void kernel_launch(void* const* d_in, const int* in_sizes, int n_in,
                              void* d_out, int out_size, void* d_ws, size_t ws_size,
                              hipStream_t stream) {
    (void)in_sizes; (void)n_in; (void)out_size; (void)ws_size;
    const float* x   = (const float*)d_in[0];
    const float* qw  = (const float*)d_in[1];
    const float* qb_ = (const float*)d_in[2];
    const float* vb_ = (const float*)d_in[3];
    const float* ls  = (const float*)d_in[4];
    const float* w1  = (const float*)d_in[5];
    const float* b1  = (const float*)d_in[6];
    const float* w2  = (const float*)d_in[7];
    const float* prw = (const float*)d_in[8];
    const float* pb  = (const float*)d_in[9];
    float* out = (float*)d_out;
    char* ws = (char*)d_ws;

    prep0<<<1024, 256, 0, stream>>>(qw, prw, qb_, vb_, ls, ws);
    prep1<<<8, 256, 0, stream>>>(w1, b1, w2, ws);
    prep2<<<128, 256, 0, stream>>>(ws);

    (void)hipFuncSetAttribute((const void*)swin_fused,
                              hipFuncAttributeMaxDynamicSharedMemorySize, 53248);
    swin_fused<<<8192, 256, 53248, stream>>>(
        x,
        (const f16*)(ws + WQ_OFF), (const f16*)(ws + PW_OFF),
        (const float*)(ws + QB_OFF), (const float*)(ws + SC_OFF),
        (const float*)(ws + BB_OFF), pb, out);
}

// Round 10
// 984.877 us; speedup vs baseline: 1.2794x; 1.0851x over previous
//
#include <hip/hip_runtime.h>
#include <hip/hip_fp16.h>

typedef _Float16 f16;
typedef _Float16 f16x8 __attribute__((ext_vector_type(8)));
typedef _Float16 f16x4 __attribute__((ext_vector_type(4)));
typedef float f32x4 __attribute__((ext_vector_type(4)));

#define L2E 1.4426950408889634f

// workspace layout (bytes)
#define WQ_OFF   0         // 768*256 f16   qkv weight, row-major [n][k]
#define PW_OFF   393216    // 256*256 f16   proj weight, row-major [n][k]
#define QB_OFF   524288    // 768 f32       concat qkv bias (k-bias = 0)
#define SC_OFF   527360    // 8 f32         exp(min(logit_scale, ln100))
#define TBL_OFF  527616    // 225*8 f32     cpb mlp table
#define BB_OFF   535040    // 32768 f32     folded bias, permuted [h][mi][nj][c][g][r]

// ---------------- prep kernels ----------------

__global__ void prep0(const float* __restrict__ qw, const float* __restrict__ prw,
                      const float* __restrict__ qbias, const float* __restrict__ vbias,
                      const float* __restrict__ ls, char* __restrict__ ws) {
    int t = blockIdx.x * 256 + threadIdx.x;
    f16* wq = (f16*)(ws + WQ_OFF);
    f16* pw = (f16*)(ws + PW_OFF);
    if (t < 196608) wq[t] = (f16)qw[t];
    else            pw[t - 196608] = (f16)prw[t - 196608];
    if (t < 768) {
        float b = t < 256 ? qbias[t] : (t < 512 ? 0.f : vbias[t - 512]);
        ((float*)(ws + QB_OFF))[t] = b;
    }
    if (t < 8) ((float*)(ws + SC_OFF))[t] = expf(fminf(ls[t], 4.6051701859880914f));
}

__device__ __forceinline__ float norm_coord(int u) { // u in 0..14
    float v = (float)(u - 7) * (8.0f / 7.0f);
    float s = (v > 0.f) ? 1.f : ((v < 0.f) ? -1.f : 0.f);
    return s * log2f(fabsf(v) + 1.f) * (1.f / 3.f);
}

__global__ void prep1(const float* __restrict__ w1, const float* __restrict__ b1,
                      const float* __restrict__ w2, char* __restrict__ ws) {
    int t = blockIdx.x * 256 + threadIdx.x; // 1800 used
    if (t >= 1800) return;
    int p = t >> 3, h = t & 7;
    float ta = norm_coord(p / 15);
    float tb = norm_coord(p % 15);
    float acc = 0.f;
    for (int j = 0; j < 512; ++j) {
        float hv = fmaf(w1[2 * j], ta, fmaf(w1[2 * j + 1], tb, b1[j]));
        acc = fmaf(fmaxf(hv, 0.f), w2[h * 512 + j], acc);
    }
    ((float*)(ws + TBL_OFF))[p * 8 + h] = acc;
}

__global__ void prep2(char* __restrict__ ws) {
    int t = blockIdx.x * 256 + threadIdx.x; // 32768 = 8*64*64
    int h = t >> 12, i = (t >> 6) & 63, j = t & 63;
    int ri = ((i >> 3) - (j >> 3) + 7) * 15 + ((i & 7) - (j & 7) + 7);
    float bv = ((const float*)(ws + TBL_OFF))[ri * 8 + h];
    float sg = 1.f / (1.f + expf(-bv));
    float sch = ((const float*)(ws + SC_OFF))[h];
    // +14.0: scale all e by 2^14 so the f16-rounded P stays in normal range;
    // the factor cancels exactly in O * 1/rowsum (rowsum uses the same scaled e).
    float val = (16.f * sg - sch - 16.f) * L2E + 14.0f;
    // permuted layout [h][mi][nj][c][g][r] for coalesced f32x4-over-r loads
    int mi = i >> 4, g = (i >> 2) & 3, r = i & 3;
    int nj = j >> 4, c = j & 15;
    int off = h * 4096 + mi * 1024 + nj * 256 + c * 16 + g * 4 + r;
    ((float*)(ws + BB_OFF))[off] = val;
}

// ---------------- register-exchange helpers ----------------
// packh4: f32x4 -> packed f16x4 as two u32 (RNE via (f16) casts)
__device__ __forceinline__ void packh4(f32x4 v, unsigned &lo, unsigned &hi) {
    union { f16x4 h; unsigned u[2]; } t;
    t.h[0] = (f16)v[0]; t.h[1] = (f16)v[1]; t.h[2] = (f16)v[2]; t.h[3] = (f16)v[3];
    lo = t.u[0]; hi = t.u[1];
}
// xchg4: build an MFMA A/B fragment (f16x8, k = 8 contiguous) from C-layout
// packed quads. Source value (tile p, lane(g_s,c), reg r) holds k = p*16+g_s*4+r;
// dest lane (g,c) needs k in [8g, 8g+8): p = g>>1, lower quad from lane
// (2(g&1), c), upper from (2(g&1)+1, c).  p0* = tile0 quad, p1* = tile1 quad.
__device__ __forceinline__ f16x8 xchg4(unsigned p0l, unsigned p0h,
                                       unsigned p1l, unsigned p1h,
                                       int g, int c) {
    int sLo = ((g & 1) << 5) + c;
    int sHi = sLo + 16;
    unsigned a0 = (unsigned)__shfl((int)p0l, sLo), a1 = (unsigned)__shfl((int)p0h, sLo);
    unsigned b0 = (unsigned)__shfl((int)p1l, sLo), b1 = (unsigned)__shfl((int)p1h, sLo);
    unsigned c0 = (unsigned)__shfl((int)p0l, sHi), c1 = (unsigned)__shfl((int)p0h, sHi);
    unsigned d0 = (unsigned)__shfl((int)p1l, sHi), d1 = (unsigned)__shfl((int)p1h, sHi);
    bool up = g >= 2;
    union { f16x8 h; unsigned u[4]; } r;
    r.u[0] = up ? b0 : a0; r.u[1] = up ? b1 : a1;
    r.u[2] = up ? d0 : c0; r.u[3] = up ? d1 : c1;
    return r.h;
}

// ---------------- fused main kernel ----------------
// 1 block = 1 window, 256 threads = 4 waves; wave w runs heads w and w+4.
// LDS (53248 B):
//   [0, 32768)      : x f16 [64][256] swz -> O f16 (same region) -> f32 staging
//   [32768, 53248)  : per-wave 5120 B scratch (P tiles only)
// Occupancy model (R1..R8): waves/SIMD = 512/(archVGPR+AGPR) rounded DOWN to a
// power of 2; our ~150 total lands at 2 waves/SIMD regardless of AGPR (R8
// proved AGPR 64->32 changes nothing). So this round keeps (256,2) + R6's
// proj (AGPR 64, proven 772 us) and attacks LATENCY instead: Q/K/V pack->read
// LDS round-trips (~9 lgkm(0) stalls + 72 scalar ds_writes per wave-head) are
// replaced by in-register exchanges: Q/K computed TRANSPOSED (swap MFMA
// operands; X^T B-frags == X A-frags byte-for-byte), then one 8-shfl+4-select
// cross-g exchange yields the QK/PV fragments directly. Only P uses scratch.
#define SWZ(row) (((row) & 7) << 4)
#define LGKM0() asm volatile("s_waitcnt lgkmcnt(0)" ::: "memory")

__global__ __launch_bounds__(256, 2)
void swin_fused(const float* __restrict__ x, const f16* __restrict__ wq,
                const f16* __restrict__ pw, const float* __restrict__ qb,
                const float* __restrict__ sc, const float* __restrict__ bb2,
                const float* __restrict__ pb, float* __restrict__ out) {
    extern __shared__ char lds[];
    const int tid = threadIdx.x;      // 0..255
    const int lane = tid & 63;
    const int w = tid >> 6;           // wave 0..3
    const int g = lane >> 4;
    const int c = lane & 15;
    const int win = blockIdx.x;
    char* scr = lds + 32768 + w * 5120;

    // ---- phase 0: stage x -> LDS fp16 (swizzled) ----
    const float* xw = x + (size_t)win * 16384;
    #pragma unroll
    for (int it = 0; it < 16; ++it) {
        int e4 = tid + it * 256;
        float4 v = ((const float4*)xw)[e4];
        int eidx = e4 * 4;
        int row = eidx >> 8, col = eidx & 255;
        f16x4 h4 = {(f16)v.x, (f16)v.y, (f16)v.z, (f16)v.w};
        int off = ((row << 9) + (col << 1)) ^ SWZ(row);
        *(f16x4*)(lds + off) = h4;
    }
    __syncthreads(); // (1)

    f16x4 po[4][2]; // head-0 packed O (carried through head-1): [mi][dt] x 4 r-vals

    for (int hh = 0; hh < 2; ++hh) {
        const int h = w + hh * 4;
        f16x8 vf[2][2], qf[4], kf[4];

        // ---- V GEMM (C = X * Wv^T, rows=tokens, cols=d) -> register exchange ----
        {
            f32x4 av[2][4] = {};
            #pragma unroll 2
            for (int kk = 0; kk < 8; ++kk) {
                int kb = kk * 32 + g * 8;
                f16x8 a[4];
                #pragma unroll
                for (int mi = 0; mi < 4; ++mi) {
                    int row = mi * 16 + c;
                    int off = ((row << 9) + (kb << 1)) ^ SWZ(row);
                    a[mi] = *(const f16x8*)(lds + off);
                }
                #pragma unroll
                for (int t = 0; t < 2; ++t) {
                    f16x8 b = *(const f16x8*)(wq + (size_t)(512 + h * 32 + t * 16 + c) * 256 + kb);
                    #pragma unroll
                    for (int mi = 0; mi < 4; ++mi)
                        av[t][mi] = __builtin_amdgcn_mfma_f32_16x16x32_f16(a[mi], b, av[t][mi], 0, 0, 0);
                }
            }
            // v-bias (per d-col = t*16+c)
            #pragma unroll
            for (int t = 0; t < 2; ++t) {
                float bias = qb[512 + h * 32 + t * 16 + c];
                #pragma unroll
                for (int mi = 0; mi < 4; ++mi)
                    #pragma unroll
                    for (int r = 0; r < 4; ++r) av[t][mi][r] += bias;
            }
            // pack + exchange: vf[dt][kt] B-frag (n=d=dt*16+c, k=token kt*32+8g+j);
            // source token = mi*16 + g_s*4 + r with mi = 2kt + (g>>1).
            unsigned pv[2][4][2];
            #pragma unroll
            for (int t = 0; t < 2; ++t)
                #pragma unroll
                for (int mi = 0; mi < 4; ++mi)
                    packh4(av[t][mi], pv[t][mi][0], pv[t][mi][1]);
            #pragma unroll
            for (int dt = 0; dt < 2; ++dt)
                #pragma unroll
                for (int kt = 0; kt < 2; ++kt)
                    vf[dt][kt] = xchg4(pv[dt][2 * kt][0], pv[dt][2 * kt][1],
                                       pv[dt][2 * kt + 1][0], pv[dt][2 * kt + 1][1], g, c);
        }

        // ---- Q^T GEMM (C = Wq_h * X^T: rows=d(32), cols=tokens(64)) ----
        {
            f32x4 aq[2][4] = {}; // [mt][nt]
            #pragma unroll 2
            for (int kk = 0; kk < 8; ++kk) {
                int kb = kk * 32 + g * 8;
                f16x8 a[4];
                #pragma unroll
                for (int nt = 0; nt < 4; ++nt) {
                    int row = nt * 16 + c;
                    int off = ((row << 9) + (kb << 1)) ^ SWZ(row);
                    a[nt] = *(const f16x8*)(lds + off);
                }
                #pragma unroll
                for (int mt = 0; mt < 2; ++mt) {
                    f16x8 bq = *(const f16x8*)(wq + (size_t)(h * 32 + mt * 16 + c) * 256 + kb);
                    #pragma unroll
                    for (int nt = 0; nt < 4; ++nt)
                        aq[mt][nt] = __builtin_amdgcn_mfma_f32_16x16x32_f16(bq, a[nt], aq[mt][nt], 0, 0, 0);
                }
            }
            // q-bias per d = mt*16 + g*4 + r
            f32x4 qb4[2];
            #pragma unroll
            for (int mt = 0; mt < 2; ++mt)
                qb4[mt] = *(const f32x4*)(qb + h * 32 + mt * 16 + g * 4);
            #pragma unroll
            for (int mt = 0; mt < 2; ++mt)
                #pragma unroll
                for (int nt = 0; nt < 4; ++nt)
                    aq[mt][nt] += qb4[mt];
            // normalize per token (col): per-lane 8 squares + reduce over g-groups
            #pragma unroll
            for (int nt = 0; nt < 4; ++nt) {
                float pq = 0.f;
                #pragma unroll
                for (int mt = 0; mt < 2; ++mt)
                    #pragma unroll
                    for (int r = 0; r < 4; ++r) pq = fmaf(aq[mt][nt][r], aq[mt][nt][r], pq);
                pq += __shfl_xor(pq, 16);
                pq += __shfl_xor(pq, 32);
                float rq = __builtin_amdgcn_rsqf(fmaxf(pq, 1e-24f));
                #pragma unroll
                for (int mt = 0; mt < 2; ++mt) aq[mt][nt] *= rq;
            }
            // pack + exchange -> qf[nt] (A-frag: row=token nt*16+c, k=d 8g..8g+7)
            #pragma unroll
            for (int nt = 0; nt < 4; ++nt) {
                unsigned q0l, q0h, q1l, q1h;
                packh4(aq[0][nt], q0l, q0h);
                packh4(aq[1][nt], q1l, q1h);
                qf[nt] = xchg4(q0l, q0h, q1l, q1h, g, c);
            }
        }
        // ---- K^T GEMM (no bias), same pattern -> kf ----
        {
            f32x4 ak[2][4] = {};
            #pragma unroll 2
            for (int kk = 0; kk < 8; ++kk) {
                int kb = kk * 32 + g * 8;
                f16x8 a[4];
                #pragma unroll
                for (int nt = 0; nt < 4; ++nt) {
                    int row = nt * 16 + c;
                    int off = ((row << 9) + (kb << 1)) ^ SWZ(row);
                    a[nt] = *(const f16x8*)(lds + off);
                }
                #pragma unroll
                for (int mt = 0; mt < 2; ++mt) {
                    f16x8 bk = *(const f16x8*)(wq + (size_t)(256 + h * 32 + mt * 16 + c) * 256 + kb);
                    #pragma unroll
                    for (int nt = 0; nt < 4; ++nt)
                        ak[mt][nt] = __builtin_amdgcn_mfma_f32_16x16x32_f16(bk, a[nt], ak[mt][nt], 0, 0, 0);
                }
            }
            #pragma unroll
            for (int nt = 0; nt < 4; ++nt) {
                float pk = 0.f;
                #pragma unroll
                for (int mt = 0; mt < 2; ++mt)
                    #pragma unroll
                    for (int r = 0; r < 4; ++r) pk = fmaf(ak[mt][nt][r], ak[mt][nt][r], pk);
                pk += __shfl_xor(pk, 16);
                pk += __shfl_xor(pk, 32);
                float rk = __builtin_amdgcn_rsqf(fmaxf(pk, 1e-24f));
                #pragma unroll
                for (int mt = 0; mt < 2; ++mt) ak[mt][nt] *= rk;
            }
            #pragma unroll
            for (int nt = 0; nt < 4; ++nt) {
                unsigned k0l, k0h, k1l, k1h;
                packh4(ak[0][nt], k0l, k0h);
                packh4(ak[1][nt], k1l, k1h);
                kf[nt] = xchg4(k0l, k0h, k1l, k1h, g, c);
            }
        }

        if (hh == 1) {
            // all x-reads block-wide are complete -> x-region becomes O-region
            __syncthreads(); // (2)
            const int h0 = w;
            #pragma unroll
            for (int mi = 0; mi < 4; ++mi)
                #pragma unroll
                for (int dt = 0; dt < 2; ++dt)
                    #pragma unroll
                    for (int r = 0; r < 4; ++r) {
                        int row = mi * 16 + g * 4 + r;
                        int col = h0 * 32 + dt * 16 + c;
                        int off = ((row << 9) + (col << 1)) ^ SWZ(row);
                        *(f16*)(lds + off) = po[mi][dt][r];
                    }
        }

        // ---- QK quarters -> exp (+rowsum) -> P scratch, interleaved PV ----
        const float scl2e = sc[h] * L2E;
        const float* bbw = bb2 + h * 4096;
        f32x4 oo[4][2] = {};  // [mo][dt]
        f32x4 rs[4] = {};     // rowsum partials per (mi, r)
        #pragma unroll
        for (int nj = 0; nj < 4; ++nj) {
            #pragma unroll
            for (int mi = 0; mi < 4; ++mi) {
                f32x4 z = {};
                f32x4 s = __builtin_amdgcn_mfma_f32_16x16x32_f16(qf[mi], kf[nj], z, 0, 0, 0);
                f32x4 bb4 = *(const f32x4*)(bbw + mi * 1024 + nj * 256 + c * 16 + g * 4);
                #pragma unroll
                for (int r = 0; r < 4; ++r) {
                    float e = exp2f(fmaf(s[r], scl2e, bb4[r]));
                    rs[mi][r] += e;
                    int off = (mi * 16 + g * 4 + r) * 80 + (((nj & 1) * 16 + c) << 1);
                    *(f16*)(scr + off) = (f16)e;
                }
            }
            if (nj & 1) {
                const int kt = nj >> 1;
                LGKM0();
                f16x8 pa[4];
                #pragma unroll
                for (int mo = 0; mo < 4; ++mo)
                    pa[mo] = *(const f16x8*)(scr + (mo * 16 + c) * 80 + g * 16);
                LGKM0();
                #pragma unroll
                for (int mo = 0; mo < 4; ++mo)
                    #pragma unroll
                    for (int dt = 0; dt < 2; ++dt)
                        oo[mo][dt] = __builtin_amdgcn_mfma_f32_16x16x32_f16(pa[mo], vf[dt][kt], oo[mo][dt], 0, 0, 0);
            }
        }
        // rowsum reduce (over the 16 c-lanes) -> reciprocal; normalize O
        #pragma unroll
        for (int mi = 0; mi < 4; ++mi)
            #pragma unroll
            for (int r = 0; r < 4; ++r) {
                float t = rs[mi][r];
                t += __shfl_xor(t, 1); t += __shfl_xor(t, 2);
                t += __shfl_xor(t, 4); t += __shfl_xor(t, 8);
                float ri = __builtin_amdgcn_rcpf(t);
                oo[mi][0][r] *= ri;
                oo[mi][1][r] *= ri;
            }
        if (hh == 0) {
            #pragma unroll
            for (int mi = 0; mi < 4; ++mi)
                #pragma unroll
                for (int dt = 0; dt < 2; ++dt)
                    #pragma unroll
                    for (int r = 0; r < 4; ++r)
                        po[mi][dt][r] = (f16)oo[mi][dt][r];
        } else {
            #pragma unroll
            for (int mi = 0; mi < 4; ++mi)
                #pragma unroll
                for (int dt = 0; dt < 2; ++dt)
                    #pragma unroll
                    for (int r = 0; r < 4; ++r) {
                        int row = mi * 16 + g * 4 + r;
                        int col = h * 32 + dt * 16 + c;
                        int off = ((row << 9) + (col << 1)) ^ SWZ(row);
                        *(f16*)(lds + off) = (f16)oo[mi][dt][r];
                    }
        }
    }
    __syncthreads(); // (3) O complete -> proj may read

    // ---- proj GEMM: wave w -> out cols [64w, 64w+64) (R6 epilogue) ----
    float pbias[4];
    #pragma unroll
    for (int nt = 0; nt < 4; ++nt) pbias[nt] = pb[w * 64 + nt * 16 + c];
    f32x4 pacc[4][4] = {}; // [nt][mi]
    #pragma unroll 2
    for (int kk = 0; kk < 8; ++kk) {
        int kb = kk * 32 + g * 8;
        f16x8 a[4];
        #pragma unroll
        for (int mi = 0; mi < 4; ++mi) {
            int row = mi * 16 + c;
            int off = ((row << 9) + (kb << 1)) ^ SWZ(row);
            a[mi] = *(const f16x8*)(lds + off);
        }
        #pragma unroll
        for (int nt = 0; nt < 4; ++nt) {
            f16x8 b = *(const f16x8*)(pw + (size_t)(w * 64 + nt * 16 + c) * 256 + kb);
            #pragma unroll
            for (int mi = 0; mi < 4; ++mi)
                pacc[nt][mi] = __builtin_amdgcn_mfma_f32_16x16x32_f16(a[mi], b, pacc[nt][mi], 0, 0, 0);
        }
    }
    __syncthreads(); // (4) all LDS dead -> f32 staging may overwrite

    // ---- 2-pass f32 staging (32 rows each) + full-line float4 writes ----
    #pragma unroll
    for (int p = 0; p < 2; ++p) {
        #pragma unroll
        for (int nt = 0; nt < 4; ++nt)
            #pragma unroll
            for (int m2 = 0; m2 < 2; ++m2) {
                int mi = p * 2 + m2;
                #pragma unroll
                for (int r = 0; r < 4; ++r) {
                    int row = m2 * 16 + g * 4 + r;         // 0..31 within pass
                    int col = w * 64 + nt * 16 + c;
                    int off = (row * 1024 + col * 4) ^ ((row & 7) << 4);
                    *(float*)(lds + off) = pacc[nt][mi][r] + pbias[nt];
                }
            }
        __syncthreads(); // (5)/(7)
        float4* out4 = (float4*)(out + (size_t)win * 16384 + p * 8192);
        #pragma unroll
        for (int it = 0; it < 8; ++it) {
            int e4 = it * 256 + tid;                       // 2048 float4 per pass
            int off = (e4 * 16) ^ (((e4 >> 6) & 7) << 4);
            out4[e4] = *(const float4*)(lds + off);
        }
        if (p == 0) __syncthreads(); // (6) pass-A reads done before overwrite
    }
}

// ---------------- launch ----------------

extern "C" void kernel_launch(void* const* d_in, const int* in_sizes, int n_in,
                              void* d_out, int out_size, void* d_ws, size_t ws_size,
                              hipStream_t stream) {
    (void)in_sizes; (void)n_in; (void)out_size; (void)ws_size;
    const float* x   = (const float*)d_in[0];
    const float* qw  = (const float*)d_in[1];
    const float* qb_ = (const float*)d_in[2];
    const float* vb_ = (const float*)d_in[3];
    const float* ls  = (const float*)d_in[4];
    const float* w1  = (const float*)d_in[5];
    const float* b1  = (const float*)d_in[6];
    const float* w2  = (const float*)d_in[7];
    const float* prw = (const float*)d_in[8];
    const float* pb  = (const float*)d_in[9];
    float* out = (float*)d_out;
    char* ws = (char*)d_ws;

    prep0<<<1024, 256, 0, stream>>>(qw, prw, qb_, vb_, ls, ws);
    prep1<<<8, 256, 0, stream>>>(w1, b1, w2, ws);
    prep2<<<128, 256, 0, stream>>>(ws);

    (void)hipFuncSetAttribute((const void*)swin_fused,
                              hipFuncAttributeMaxDynamicSharedMemorySize, 53248);
    swin_fused<<<8192, 256, 53248, stream>>>(
        x,
        (const f16*)(ws + WQ_OFF), (const f16*)(ws + PW_OFF),
        (const float*)(ws + QB_OFF), (const float*)(ws + SC_OFF),
        (const float*)(ws + BB_OFF), pb, out);
}

// Round 11
// 818.328 us; speedup vs baseline: 1.5398x; 1.2035x over previous
//
#include <hip/hip_runtime.h>
#include <hip/hip_fp16.h>

typedef _Float16 f16;
typedef _Float16 f16x8 __attribute__((ext_vector_type(8)));
typedef _Float16 f16x4 __attribute__((ext_vector_type(4)));
typedef float f32x4 __attribute__((ext_vector_type(4)));

#define L2E 1.4426950408889634f

// workspace layout (bytes)
#define WQ_OFF   0         // 768*256 f16   qkv weight, row-major [n][k]
#define PW_OFF   393216    // 256*256 f16   proj weight, row-major [n][k]
#define QB_OFF   524288    // 768 f32       concat qkv bias (k-bias = 0)
#define SC_OFF   527360    // 8 f32         exp(min(logit_scale, ln100))
#define TBL_OFF  527616    // 225*8 f32     cpb mlp table
#define BB_OFF   535040    // 32768 f32     folded bias, permuted [h][mi][nj][c][g][r]

// ---------------- prep kernels ----------------

__global__ void prep0(const float* __restrict__ qw, const float* __restrict__ prw,
                      const float* __restrict__ qbias, const float* __restrict__ vbias,
                      const float* __restrict__ ls, char* __restrict__ ws) {
    int t = blockIdx.x * 256 + threadIdx.x;
    f16* wq = (f16*)(ws + WQ_OFF);
    f16* pw = (f16*)(ws + PW_OFF);
    if (t < 196608) wq[t] = (f16)qw[t];
    else            pw[t - 196608] = (f16)prw[t - 196608];
    if (t < 768) {
        float b = t < 256 ? qbias[t] : (t < 512 ? 0.f : vbias[t - 512]);
        ((float*)(ws + QB_OFF))[t] = b;
    }
    if (t < 8) ((float*)(ws + SC_OFF))[t] = expf(fminf(ls[t], 4.6051701859880914f));
}

__device__ __forceinline__ float norm_coord(int u) { // u in 0..14
    float v = (float)(u - 7) * (8.0f / 7.0f);
    float s = (v > 0.f) ? 1.f : ((v < 0.f) ? -1.f : 0.f);
    return s * log2f(fabsf(v) + 1.f) * (1.f / 3.f);
}

__global__ void prep1(const float* __restrict__ w1, const float* __restrict__ b1,
                      const float* __restrict__ w2, char* __restrict__ ws) {
    int t = blockIdx.x * 256 + threadIdx.x; // 1800 used
    if (t >= 1800) return;
    int p = t >> 3, h = t & 7;
    float ta = norm_coord(p / 15);
    float tb = norm_coord(p % 15);
    float acc = 0.f;
    for (int j = 0; j < 512; ++j) {
        float hv = fmaf(w1[2 * j], ta, fmaf(w1[2 * j + 1], tb, b1[j]));
        acc = fmaf(fmaxf(hv, 0.f), w2[h * 512 + j], acc);
    }
    ((float*)(ws + TBL_OFF))[p * 8 + h] = acc;
}

__global__ void prep2(char* __restrict__ ws) {
    int t = blockIdx.x * 256 + threadIdx.x; // 32768 = 8*64*64
    int h = t >> 12, i = (t >> 6) & 63, j = t & 63;
    int ri = ((i >> 3) - (j >> 3) + 7) * 15 + ((i & 7) - (j & 7) + 7);
    float bv = ((const float*)(ws + TBL_OFF))[ri * 8 + h];
    float sg = 1.f / (1.f + expf(-bv));
    float sch = ((const float*)(ws + SC_OFF))[h];
    // +14.0: scale all e by 2^14 so the f16-rounded P stays in normal range;
    // the factor cancels exactly in O * 1/rowsum (rowsum uses the same scaled e).
    float val = (16.f * sg - sch - 16.f) * L2E + 14.0f;
    // permuted layout [h][mi][nj][c][g][r] for coalesced f32x4-over-r loads
    int mi = i >> 4, g = (i >> 2) & 3, r = i & 3;
    int nj = j >> 4, c = j & 15;
    int off = h * 4096 + mi * 1024 + nj * 256 + c * 16 + g * 4 + r;
    ((float*)(ws + BB_OFF))[off] = val;
}

// ---------------- fused main kernel ----------------
// 1 block = 1 window, 256 threads = 4 waves; wave w runs heads w and w+4.
// LDS (53248 B):
//   [0, 32768)      : x f16 [64][256] swz -> O f16 (same region) -> f32 out staging
//   [32768, 53248)  : per-wave 5120 B scratch (V^T -> Qhat -> Khat -> P per head)
// Occupancy model (R1..R10): waves/SIMD = 512/(archVGPR+AGPR) rounded DOWN to a
// power of 2. Anything in (128,256] -> 2 waves/SIMD; R6 used 188 leaving ~68
// regs idle. R10's shfl-exchange regressed (__shfl = ds_bpermute = LDS op +
// spills at the 128 boundary). This round: exact R6 skeleton (772 us proven),
// but the three per-head GEMM k-loops (V,Q,K) FUSED into one: a-frags read
// once (was 3x), 6 B-loads + 24 MFMAs per k-step -> 3x MFMA work per latency
// event. Accumulators 96 f32 fit the idle budget at unchanged occupancy.
#define SWZ(row) (((row) & 7) << 4)
#define LGKM0() asm volatile("s_waitcnt lgkmcnt(0)" ::: "memory")

__global__ __launch_bounds__(256, 2)
void swin_fused(const float* __restrict__ x, const f16* __restrict__ wq,
                const f16* __restrict__ pw, const float* __restrict__ qb,
                const float* __restrict__ sc, const float* __restrict__ bb2,
                const float* __restrict__ pb, float* __restrict__ out) {
    extern __shared__ char lds[];
    const int tid = threadIdx.x;      // 0..255
    const int lane = tid & 63;
    const int w = tid >> 6;           // wave 0..3
    const int g = lane >> 4;
    const int c = lane & 15;
    const int win = blockIdx.x;
    char* scr = lds + 32768 + w * 5120;

    // ---- phase 0: stage x -> LDS fp16 (swizzled) ----
    const float* xw = x + (size_t)win * 16384;
    #pragma unroll
    for (int it = 0; it < 16; ++it) {
        int e4 = tid + it * 256;
        float4 v = ((const float4*)xw)[e4];
        int eidx = e4 * 4;
        int row = eidx >> 8, col = eidx & 255;
        f16x4 h4 = {(f16)v.x, (f16)v.y, (f16)v.z, (f16)v.w};
        int off = ((row << 9) + (col << 1)) ^ SWZ(row);
        *(f16x4*)(lds + off) = h4;
    }
    __syncthreads(); // (1)

    f16x4 po[4][2]; // head-0 packed O (carried through head-1): [mi][dt] x 4 r-vals

    for (int hh = 0; hh < 2; ++hh) {
        const int h = w + hh * 4;
        f16x8 vf[2][2], qf[4], kf[4];

        // ---- FUSED V+Q+K GEMM: one k-loop, a-frags read once, 24 MFMA/step ----
        {
            f32x4 av[2][4] = {}, aq[2][4] = {}, ak[2][4] = {};
            #pragma unroll 2
            for (int kk = 0; kk < 8; ++kk) {
                int kb = kk * 32 + g * 8;
                f16x8 a[4];
                #pragma unroll
                for (int mi = 0; mi < 4; ++mi) {
                    int row = mi * 16 + c;
                    int off = ((row << 9) + (kb << 1)) ^ SWZ(row);
                    a[mi] = *(const f16x8*)(lds + off);
                }
                #pragma unroll
                for (int t = 0; t < 2; ++t) {
                    int ncol = h * 32 + t * 16 + c;
                    f16x8 bq = *(const f16x8*)(wq + (size_t)ncol * 256 + kb);
                    f16x8 bk = *(const f16x8*)(wq + (size_t)(256 + ncol) * 256 + kb);
                    f16x8 bv = *(const f16x8*)(wq + (size_t)(512 + ncol) * 256 + kb);
                    #pragma unroll
                    for (int mi = 0; mi < 4; ++mi) {
                        aq[t][mi] = __builtin_amdgcn_mfma_f32_16x16x32_f16(a[mi], bq, aq[t][mi], 0, 0, 0);
                        ak[t][mi] = __builtin_amdgcn_mfma_f32_16x16x32_f16(a[mi], bk, ak[t][mi], 0, 0, 0);
                        av[t][mi] = __builtin_amdgcn_mfma_f32_16x16x32_f16(a[mi], bv, av[t][mi], 0, 0, 0);
                    }
                }
            }

            // ---- V: bias, pack to V^T scratch (stride 144), read vf frags ----
            #pragma unroll
            for (int t = 0; t < 2; ++t) {
                float bias = qb[512 + h * 32 + t * 16 + c];
                #pragma unroll
                for (int mi = 0; mi < 4; ++mi) {
                    f16x4 hv;
                    #pragma unroll
                    for (int r = 0; r < 4; ++r) hv[r] = (f16)(av[t][mi][r] + bias);
                    int off = (t * 16 + c) * 144 + (mi * 16 + g * 4) * 2;
                    *(f16x4*)(scr + off) = hv;
                }
            }
            LGKM0();
            #pragma unroll
            for (int dt = 0; dt < 2; ++dt)
                #pragma unroll
                for (int kt = 0; kt < 2; ++kt)
                    vf[dt][kt] = *(const f16x8*)(scr + (dt * 16 + c) * 144 + kt * 64 + g * 16);
            LGKM0();

            // ---- Q: bias, normalize (reduce over c lanes), pack, read qf ----
            #pragma unroll
            for (int t = 0; t < 2; ++t) {
                float bias = qb[h * 32 + t * 16 + c];
                #pragma unroll
                for (int mi = 0; mi < 4; ++mi)
                    #pragma unroll
                    for (int r = 0; r < 4; ++r) aq[t][mi][r] += bias;
            }
            #pragma unroll
            for (int mi = 0; mi < 4; ++mi) {
                #pragma unroll
                for (int r = 0; r < 4; ++r) {
                    float pq = aq[0][mi][r] * aq[0][mi][r] + aq[1][mi][r] * aq[1][mi][r];
                    pq += __shfl_xor(pq, 1); pq += __shfl_xor(pq, 2);
                    pq += __shfl_xor(pq, 4); pq += __shfl_xor(pq, 8);
                    float rq = __builtin_amdgcn_rsqf(fmaxf(pq, 1e-24f));
                    aq[0][mi][r] *= rq; aq[1][mi][r] *= rq;
                }
            }
            #pragma unroll
            for (int t = 0; t < 2; ++t)
                #pragma unroll
                for (int mi = 0; mi < 4; ++mi)
                    #pragma unroll
                    for (int r = 0; r < 4; ++r) {
                        int off = (mi * 16 + g * 4 + r) * 80 + (t * 16 + c) * 2;
                        *(f16*)(scr + off) = (f16)aq[t][mi][r];
                    }
            LGKM0();
            #pragma unroll
            for (int mi = 0; mi < 4; ++mi)
                qf[mi] = *(const f16x8*)(scr + (mi * 16 + c) * 80 + g * 16);
            LGKM0();

            // ---- K: normalize (k bias zero), pack, read kf ----
            #pragma unroll
            for (int mi = 0; mi < 4; ++mi) {
                #pragma unroll
                for (int r = 0; r < 4; ++r) {
                    float pk = ak[0][mi][r] * ak[0][mi][r] + ak[1][mi][r] * ak[1][mi][r];
                    pk += __shfl_xor(pk, 1); pk += __shfl_xor(pk, 2);
                    pk += __shfl_xor(pk, 4); pk += __shfl_xor(pk, 8);
                    float rk = __builtin_amdgcn_rsqf(fmaxf(pk, 1e-24f));
                    ak[0][mi][r] *= rk; ak[1][mi][r] *= rk;
                }
            }
            #pragma unroll
            for (int t = 0; t < 2; ++t)
                #pragma unroll
                for (int mi = 0; mi < 4; ++mi)
                    #pragma unroll
                    for (int r = 0; r < 4; ++r) {
                        int off = (mi * 16 + g * 4 + r) * 80 + (t * 16 + c) * 2;
                        *(f16*)(scr + off) = (f16)ak[t][mi][r];
                    }
            LGKM0();
            #pragma unroll
            for (int nj = 0; nj < 4; ++nj)
                kf[nj] = *(const f16x8*)(scr + (nj * 16 + c) * 80 + g * 16);
            LGKM0();
        }

        if (hh == 1) {
            // all x-reads block-wide are complete -> x-region becomes O-region
            __syncthreads(); // (2)
            const int h0 = w;
            #pragma unroll
            for (int mi = 0; mi < 4; ++mi)
                #pragma unroll
                for (int dt = 0; dt < 2; ++dt)
                    #pragma unroll
                    for (int r = 0; r < 4; ++r) {
                        int row = mi * 16 + g * 4 + r;
                        int col = h0 * 32 + dt * 16 + c;
                        int off = ((row << 9) + (col << 1)) ^ SWZ(row);
                        *(f16*)(lds + off) = po[mi][dt][r];
                    }
        }

        // ---- QK quarters -> exp -> P scratch, interleaved PV (+ ones-col rowsum) ----
        const float scl2e = sc[h] * L2E;
        const float* bbw = bb2 + h * 4096;
        f32x4 oo[4][2] = {};  // [mo][dt]
        f32x4 oaux[4] = {};   // ones-column: col-0 lanes accumulate rowsum
        f16 onev = (c == 0) ? (f16)1.f : (f16)0.f;
        f16x8 von = {onev, onev, onev, onev, onev, onev, onev, onev};
        #pragma unroll
        for (int nj = 0; nj < 4; ++nj) {
            #pragma unroll
            for (int mi = 0; mi < 4; ++mi) {
                f32x4 z = {};
                f32x4 s = __builtin_amdgcn_mfma_f32_16x16x32_f16(qf[mi], kf[nj], z, 0, 0, 0);
                f32x4 bb4 = *(const f32x4*)(bbw + mi * 1024 + nj * 256 + c * 16 + g * 4);
                #pragma unroll
                for (int r = 0; r < 4; ++r) {
                    float e = exp2f(fmaf(s[r], scl2e, bb4[r]));
                    int off = (mi * 16 + g * 4 + r) * 80 + (((nj & 1) * 16 + c) << 1);
                    *(f16*)(scr + off) = (f16)e;
                }
            }
            if (nj & 1) {
                const int kt = nj >> 1;
                LGKM0();
                f16x8 pa[4];
                #pragma unroll
                for (int mo = 0; mo < 4; ++mo)
                    pa[mo] = *(const f16x8*)(scr + (mo * 16 + c) * 80 + g * 16);
                LGKM0();
                #pragma unroll
                for (int mo = 0; mo < 4; ++mo) {
                    #pragma unroll
                    for (int dt = 0; dt < 2; ++dt)
                        oo[mo][dt] = __builtin_amdgcn_mfma_f32_16x16x32_f16(pa[mo], vf[dt][kt], oo[mo][dt], 0, 0, 0);
                    oaux[mo] = __builtin_amdgcn_mfma_f32_16x16x32_f16(pa[mo], von, oaux[mo], 0, 0, 0);
                }
            }
        }
        // rowsum broadcast from col-0 lane of each g-group; normalize O
        #pragma unroll
        for (int mo = 0; mo < 4; ++mo)
            #pragma unroll
            for (int r = 0; r < 4; ++r) {
                float rsum = __shfl(oaux[mo][r], lane & 48);
                float ri = __builtin_amdgcn_rcpf(rsum);
                oo[mo][0][r] *= ri;
                oo[mo][1][r] *= ri;
            }
        if (hh == 0) {
            #pragma unroll
            for (int mi = 0; mi < 4; ++mi)
                #pragma unroll
                for (int dt = 0; dt < 2; ++dt)
                    #pragma unroll
                    for (int r = 0; r < 4; ++r)
                        po[mi][dt][r] = (f16)oo[mi][dt][r];
        } else {
            #pragma unroll
            for (int mi = 0; mi < 4; ++mi)
                #pragma unroll
                for (int dt = 0; dt < 2; ++dt)
                    #pragma unroll
                    for (int r = 0; r < 4; ++r) {
                        int row = mi * 16 + g * 4 + r;
                        int col = h * 32 + dt * 16 + c;
                        int off = ((row << 9) + (col << 1)) ^ SWZ(row);
                        *(f16*)(lds + off) = (f16)oo[mi][dt][r];
                    }
        }
    }
    __syncthreads(); // (3) O complete -> proj may read

    // ---- proj GEMM: wave w -> out cols [64w, 64w+64) ----
    float pbias[4];
    #pragma unroll
    for (int nt = 0; nt < 4; ++nt) pbias[nt] = pb[w * 64 + nt * 16 + c];
    f32x4 pacc[4][4] = {}; // [nt][mi]
    #pragma unroll 2
    for (int kk = 0; kk < 8; ++kk) {
        int kb = kk * 32 + g * 8;
        f16x8 a[4];
        #pragma unroll
        for (int mi = 0; mi < 4; ++mi) {
            int row = mi * 16 + c;
            int off = ((row << 9) + (kb << 1)) ^ SWZ(row);
            a[mi] = *(const f16x8*)(lds + off);
        }
        #pragma unroll
        for (int nt = 0; nt < 4; ++nt) {
            f16x8 b = *(const f16x8*)(pw + (size_t)(w * 64 + nt * 16 + c) * 256 + kb);
            #pragma unroll
            for (int mi = 0; mi < 4; ++mi)
                pacc[nt][mi] = __builtin_amdgcn_mfma_f32_16x16x32_f16(a[mi], b, pacc[nt][mi], 0, 0, 0);
        }
    }
    __syncthreads(); // (4) all LDS dead -> f32 staging may overwrite

    // ---- 2-pass f32 staging (32 rows each) + full-line float4 writes ----
    #pragma unroll
    for (int p = 0; p < 2; ++p) {
        #pragma unroll
        for (int nt = 0; nt < 4; ++nt)
            #pragma unroll
            for (int m2 = 0; m2 < 2; ++m2) {
                int mi = p * 2 + m2;
                #pragma unroll
                for (int r = 0; r < 4; ++r) {
                    int row = m2 * 16 + g * 4 + r;         // 0..31 within pass
                    int col = w * 64 + nt * 16 + c;
                    int off = (row * 1024 + col * 4) ^ ((row & 7) << 4);
                    *(float*)(lds + off) = pacc[nt][mi][r] + pbias[nt];
                }
            }
        __syncthreads(); // (5)/(7)
        float4* out4 = (float4*)(out + (size_t)win * 16384 + p * 8192);
        #pragma unroll
        for (int it = 0; it < 8; ++it) {
            int e4 = it * 256 + tid;                       // 2048 float4 per pass
            int off = (e4 * 16) ^ (((e4 >> 6) & 7) << 4);
            out4[e4] = *(const float4*)(lds + off);
        }
        if (p == 0) __syncthreads(); // (6) pass-A reads done before overwrite
    }
}

// ---------------- launch ----------------

extern "C" void kernel_launch(void* const* d_in, const int* in_sizes, int n_in,
                              void* d_out, int out_size, void* d_ws, size_t ws_size,
                              hipStream_t stream) {
    (void)in_sizes; (void)n_in; (void)out_size; (void)ws_size;
    const float* x   = (const float*)d_in[0];
    const float* qw  = (const float*)d_in[1];
    const float* qb_ = (const float*)d_in[2];
    const float* vb_ = (const float*)d_in[3];
    const float* ls  = (const float*)d_in[4];
    const float* w1  = (const float*)d_in[5];
    const float* b1  = (const float*)d_in[6];
    const float* w2  = (const float*)d_in[7];
    const float* prw = (const float*)d_in[8];
    const float* pb  = (const float*)d_in[9];
    float* out = (float*)d_out;
    char* ws = (char*)d_ws;

    prep0<<<1024, 256, 0, stream>>>(qw, prw, qb_, vb_, ls, ws);
    prep1<<<8, 256, 0, stream>>>(w1, b1, w2, ws);
    prep2<<<128, 256, 0, stream>>>(ws);

    (void)hipFuncSetAttribute((const void*)swin_fused,
                              hipFuncAttributeMaxDynamicSharedMemorySize, 53248);
    swin_fused<<<8192, 256, 53248, stream>>>(
        x,
        (const f16*)(ws + WQ_OFF), (const f16*)(ws + PW_OFF),
        (const float*)(ws + QB_OFF), (const float*)(ws + SC_OFF),
        (const float*)(ws + BB_OFF), pb, out);
}